// Round 6
// baseline (137.002 us; speedup 1.0000x reference)
//
#include <hip/hip_runtime.h>

typedef float v2f __attribute__((ext_vector_type(2)));
typedef float v4f __attribute__((ext_vector_type(4)));
#define PKFMA(a,b,c) __builtin_elementwise_fma((a),(b),(c))
#define PKMAX(a,b)   __builtin_elementwise_max((a),(b))
static __device__ __forceinline__ v2f vsplat(float s) { return (v2f){s, s}; }
static __device__ __forceinline__ v4f v4splat(float s) { return (v4f){s, s, s, s}; }
static __device__ __forceinline__ v2f vmk(float a, float b) { return (v2f){a, b}; }
static __device__ __forceinline__ v2f shfl_xor_v2(v2f x, int m) {
    double d = __builtin_bit_cast(double, x);
    d = __shfl_xor(d, m, 64);
    return __builtin_bit_cast(v2f, d);
}
// sum across the lane^32 split (both halves end with the full sum)
static __device__ __forceinline__ v2f red32_v2(v2f x) { return x + shfl_xor_v2(x, 32); }
static __device__ __forceinline__ v4f red32_v4(v4f x) {
    v2f lo = vmk(x.x, x.y), hi = vmk(x.z, x.w);
    lo = red32_v2(lo);  hi = red32_v2(hi);
    return (v4f){lo.x, lo.y, hi.x, hi.y};
}
// wave-wide register broadcast: read 'v' from physical lane 'lane' (uniform index)
static __device__ __forceinline__ float RL(float v, int lane) {
    return __builtin_bit_cast(float, __builtin_amdgcn_readlane(__builtin_bit_cast(int, v), lane));
}

// ---------------- workspace float offsets ----------------
#define WS_WQC   0        // wq@w_iq          128x128 row-major
#define WS_WKC   16384    // wk@w_ik          128x128 row-major
#define WS_WVC   32768    // wv@w_iv          128x128 row-major
#define WS_MOW   49152    // mha_out_w@out_w  128x128 row-major
#define WS_GQ    65536    // [64][128]: cols 0..63 G, 64..95 Gs, 96..127 Gd
#define WS_G0Q   73728    // [128] biases in same col order
#define WS_FALL  73856    // [128][128]: rows 0..31 Fsp, 32..63 Fdv, 64..127 Fhid
#define WS_FB    90240    // [128]
#define WS_PA    90368    // [8192][128]: cols 0..63 pool(ssp|sdv), 64..127 ah
#define WS_HID   1138944  // [128 batches][64][64] relu(hs@w_hid+b_hid)
#define WS_NEED_HID_BYTES ((size_t)(1138944 + 128*64*64) * 4)

// P1: weight products (+ per-batch hid into ws when workspace allows)
__global__ __launch_bounds__(256) void precompute1(
    const float* __restrict__ wq, const float* __restrict__ wk,
    const float* __restrict__ wv, const float* __restrict__ in_proj_w,
    const float* __restrict__ mha_out_w, const float* __restrict__ out_w,
    const float* __restrict__ hs, const float* __restrict__ w_hid,
    const float* __restrict__ b_hid, float* __restrict__ ws)
{
    __shared__ __align__(16) float sbuf[4224];
    const int tid = threadIdx.x;

    if (blockIdx.x < 256) {
        const int mat  = blockIdx.x >> 6;
        const int rp   = blockIdx.x & 63;
        const int rsel = tid >> 7;
        const int col  = tid & 127;
        const int r    = 2 * rp + rsel;
        const float* A; const float* Bm; int ldb; float* C;
        if (mat == 0)      { A = wq;        Bm = in_proj_w;       ldb = 384; C = ws + WS_WQC; }
        else if (mat == 1) { A = wk;        Bm = in_proj_w + 128; ldb = 384; C = ws + WS_WKC; }
        else if (mat == 2) { A = wv;        Bm = in_proj_w + 256; ldb = 384; C = ws + WS_WVC; }
        else               { A = mha_out_w; Bm = out_w;           ldb = 128; C = ws + WS_MOW; }
        sbuf[tid] = A[r * 128 + col];
        __syncthreads();
        float acc = 0.f;
        #pragma unroll 8
        for (int d = 0; d < 128; ++d) acc = fmaf(sbuf[rsel * 128 + d], Bm[d * ldb + col], acc);
        C[r * 128 + col] = acc;
    } else {
        const int b2 = blockIdx.x - 256;
        const int b = b2 >> 1, half = b2 & 1;
        const float4* src = (const float4*)(hs + b * 8192 + half * 4096);
        for (int k = tid; k < 1024; k += 256) {
            const int row = k >> 5, c = k & 31;
            *(float4*)&sbuf[row * 132 + 4 * c] = src[k];
        }
        __syncthreads();
        const int ty = tid >> 4, tx = tid & 15;
        float a0c[4] = {0,0,0,0}, a1c[4] = {0,0,0,0};
        for (int d0 = 0; d0 < 128; d0 += 4) {
            const float4 a0 = *(const float4*)&sbuf[(2*ty+0)*132 + d0];
            const float4 a1 = *(const float4*)&sbuf[(2*ty+1)*132 + d0];
            const float* a0p = (const float*)&a0;
            const float* a1p = (const float*)&a1;
            #pragma unroll
            for (int dd = 0; dd < 4; ++dd) {
                const float4 w4 = *(const float4*)&w_hid[(d0+dd)*64 + 4*tx];
                a0c[0] = fmaf(a0p[dd], w4.x, a0c[0]); a0c[1] = fmaf(a0p[dd], w4.y, a0c[1]);
                a0c[2] = fmaf(a0p[dd], w4.z, a0c[2]); a0c[3] = fmaf(a0p[dd], w4.w, a0c[3]);
                a1c[0] = fmaf(a1p[dd], w4.x, a1c[0]); a1c[1] = fmaf(a1p[dd], w4.y, a1c[1]);
                a1c[2] = fmaf(a1p[dd], w4.z, a1c[2]); a1c[3] = fmaf(a1p[dd], w4.w, a1c[3]);
            }
        }
        const float4 bh = *(const float4*)&b_hid[4*tx];
        float* dst = ws + WS_HID + b * 4096 + (32*half + 2*ty) * 64 + 4*tx;
        *(float4*)dst        = make_float4(fmaxf(a0c[0]+bh.x,0.f), fmaxf(a0c[1]+bh.y,0.f),
                                           fmaxf(a0c[2]+bh.z,0.f), fmaxf(a0c[3]+bh.w,0.f));
        *(float4*)(dst + 64) = make_float4(fmaxf(a1c[0]+bh.x,0.f), fmaxf(a1c[1]+bh.y,0.f),
                                           fmaxf(a1c[2]+bh.z,0.f), fmaxf(a1c[3]+bh.w,0.f));
    }
}

// P2: derived fused tensors GQ / g0q / F_all / fb (float4 row reads)
__global__ __launch_bounds__(128) void precompute2(
    const float* __restrict__ b_sp, const float* __restrict__ b_vel,
    const float* __restrict__ in_proj_b, const float* __restrict__ mha_out_b,
    const float* __restrict__ out_w, const float* __restrict__ out_b,
    float* __restrict__ ws)
{
    const float* Wqc = ws + WS_WQC;
    const float* Wkc = ws + WS_WKC;
    const float* Wvc = ws + WS_WVC;
    const float* Mow = ws + WS_MOW;
    const int bid = blockIdx.x, tid = threadIdx.x;
    __shared__ __align__(16) float sa[128];

    if (bid < 64) {
        const int k = bid;
        sa[tid] = Wqc[(32 + k) * 128 + tid];
        __syncthreads();
        const int j = tid;
        const int pj = (j < 64) ? 32 + j : ((j < 96) ? j - 64 : j);
        const float* brow = Wkc + pj * 128;
        float acc = 0.f;
        #pragma unroll 8
        for (int d = 0; d < 128; d += 4) {
            const float4 a4 = *(const float4*)&sa[d];
            const float4 b4 = *(const float4*)&brow[d];
            acc = fmaf(a4.x, b4.x, fmaf(a4.y, b4.y, fmaf(a4.z, b4.z, fmaf(a4.w, b4.w, acc))));
        }
        ws[WS_GQ + k * 128 + j] = acc;
    } else if (bid < 192) {
        const int k2 = bid - 64;
        const int srcRow = (k2 < 32) ? k2 : ((k2 < 64) ? 96 + (k2 - 32) : 32 + (k2 - 64));
        sa[tid] = Wvc[srcRow * 128 + tid];
        __syncthreads();
        float acc = 0.f;
        #pragma unroll 8
        for (int m = 0; m < 128; ++m) acc = fmaf(sa[m], Mow[m * 128 + tid], acc);
        ws[WS_FALL + k2 * 128 + tid] = acc;
    } else if (bid == 192) {
        float acc = out_b[tid];
        #pragma unroll 8
        for (int m = 0; m < 128; ++m) {
            acc = fmaf(in_proj_b[256 + m], Mow[m * 128 + tid], acc);
            acc = fmaf(mha_out_b[m], out_w[m * 128 + tid], acc);
        }
        ws[WS_FB + tid] = acc;
    } else {
        float qc = in_proj_b[tid];  // b_iq
        #pragma unroll 4
        for (int s = 0; s < 32; ++s) {
            qc = fmaf(fmaxf(b_sp[s], 0.f),  Wqc[s * 128 + tid], qc);
            qc = fmaf(fmaxf(b_vel[s], 0.f), Wqc[(96 + s) * 128 + tid], qc);
        }
        sa[tid] = qc;
        __syncthreads();
        const int j = tid;
        const int pj = (j < 64) ? 32 + j : ((j < 96) ? j - 64 : j);
        const float* brow = Wkc + pj * 128;
        float acc = 0.f;
        #pragma unroll 8
        for (int d = 0; d < 128; d += 4) {
            const float4 a4 = *(const float4*)&sa[d];
            const float4 b4 = *(const float4*)&brow[d];
            acc = fmaf(a4.x, b4.x, fmaf(a4.y, b4.y, fmaf(a4.z, b4.z, fmaf(a4.w, b4.w, acc))));
        }
        ws[WS_G0Q + j] = acc;
    }
}

// ---------------- attn_core v10: ph7 excised to out_gemm; Fall not staged ----------------
// v9 post-mortem: 6a-readlane regressed (+8us) -> revert 6a to v7 LDS j-split.
// ph7 was the largest combined consumer (64KB of the 97KB staging + 2MB/block LDS
// stream + ~1k VALU cy/wave). It is structurally an 8192x128 @ 128x128 GEMM ->
// moved to out_gemm. attn_core writes pool||ah rows to ws[WS_PA] (coalesced).
// LDS 141.8KB -> 59.4KB.
#define L_GQ   0        // [64][128]
#define L_G0Q  8192     // [128]
#define L_HID  8320     // [64][66] (stride-66 padded)
#define L_OBS  12544    // [64][4] = {o2x,o2y,vx,vy}
#define L_AA   12800    // + w*128 : aa[64][2]
#define L_TOT  14848    // floats = 59,392 B

template <bool HIDWS>
__global__ __launch_bounds__(1024) void attn_core(
    const float* __restrict__ hs, const float* __restrict__ obs1,
    const float* __restrict__ obs2,
    const float* __restrict__ w_sp, const float* __restrict__ b_sp,
    const float* __restrict__ w_vel, const float* __restrict__ b_vel,
    const float* __restrict__ w_hid, const float* __restrict__ b_hid,
    const float* __restrict__ ws, float* __restrict__ pa)
{
    const int tid = threadIdx.x;
    const int l   = tid & 63;
    const int w   = tid >> 6;                 // 0..15
    const int b   = blockIdx.x >> 1;
    const int rg0 = (blockIdx.x & 1) * 32 + 2 * w;   // 2 rows: rg0, rg0+1 (rg0 even)

    __shared__ __align__(16) float smem[L_TOT];
    float* const s_gq  = smem + L_GQ;
    float* const s_g0q = smem + L_G0Q;
    float* const s_hid = smem + L_HID;            // stride 66
    float* const s_obs = smem + L_OBS;
    float* const aa = smem + L_AA + w * 128;      // [j][2]

    // ---- staging: ws[WS_GQ .. WS_GQ+8320) contiguous = GQ|g0q ----
    {
        const float4* src = (const float4*)(ws + WS_GQ);
        float4* dst = (float4*)smem;
        #pragma unroll
        for (int k = tid; k < 2080; k += 1024) dst[k] = src[k];
    }
    if (tid < 64) {
        const int g = b * 64 + tid;
        const float2 o2 = ((const float2*)obs2)[g];
        const float2 o1 = ((const float2*)obs1)[g];
        *(float4*)&s_obs[tid * 4] = make_float4(o2.x, o2.y, o2.x - o1.x, o2.y - o1.y);
    }
    if (HIDWS) {
        const float4* src = (const float4*)(ws + WS_HID + b * 4096);
        {
            const int k = tid;   // exactly 1024 float4s
            const int row = k >> 4, c4 = (k & 15) * 4;
            const float4 v = src[k];
            *(v2f*)&s_hid[row * 66 + c4]     = vmk(v.x, v.y);
            *(v2f*)&s_hid[row * 66 + c4 + 2] = vmk(v.z, v.w);
        }
    } else {
        const int r = tid >> 4, c0 = (tid & 15) * 4;
        float acc[4];
        #pragma unroll
        for (int c = 0; c < 4; ++c) acc[c] = b_hid[c0 + c];
        for (int k = 0; k < 128; ++k) {
            const float a = hs[b * 8192 + r * 128 + k];
            const float4 w4 = *(const float4*)&w_hid[k * 64 + c0];
            acc[0] = fmaf(a, w4.x, acc[0]);
            acc[1] = fmaf(a, w4.y, acc[1]);
            acc[2] = fmaf(a, w4.z, acc[2]);
            acc[3] = fmaf(a, w4.w, acc[3]);
        }
        *(v2f*)&s_hid[r * 66 + c0]     = vmk(fmaxf(acc[0], 0.f), fmaxf(acc[1], 0.f));
        *(v2f*)&s_hid[r * 66 + c0 + 2] = vmk(fmaxf(acc[2], 0.f), fmaxf(acc[3], 0.f));
    }
    __syncthreads();
    // ---- no more block barriers: wave-private phases below ----

    const int kh = l >> 5;            // k-half selector
    const int cg = (l & 31) * 4;      // 4-col group
    const int hsel = l >> 5;          // row selector after reduction

    // ---- phase 3: [t | qs | qd](2x128) = hid[rg0..rg0+1] @ GQ + g0q  (registers only) ----
    v4f rres;
    {
        v4f acc0 = {0,0,0,0}, acc1 = acc0;
        const int kb = 32 * kh;
        #pragma unroll
        for (int c8 = 0; c8 < 32; c8 += 8) {
            v2f h0[4], h1[4];
            #pragma unroll
            for (int j = 0; j < 4; ++j) {
                h0[j] = *(const v2f*)&s_hid[(rg0 + 0) * 66 + kb + c8 + 2 * j];
                h1[j] = *(const v2f*)&s_hid[(rg0 + 1) * 66 + kb + c8 + 2 * j];
            }
            #pragma unroll
            for (int j = 0; j < 4; ++j) {
                const int kk = kb + c8 + 2 * j;
                const v4f ga = *(const v4f*)&s_gq[kk * 128 + cg];
                const v4f gb = *(const v4f*)&s_gq[(kk + 1) * 128 + cg];
                acc0 = PKFMA(v4splat(h0[j].x), ga, PKFMA(v4splat(h0[j].y), gb, acc0));
                acc1 = PKFMA(v4splat(h1[j].x), ga, PKFMA(v4splat(h1[j].y), gb, acc1));
            }
        }
        acc0 = red32_v4(acc0);
        acc1 = red32_v4(acc1);
        const v4f bias = *(const v4f*)&s_g0q[cg];
        rres = (hsel ? acc1 : acc0) + bias;
    }

    // ---- phase 4: sc[r] = t[r] . hid[l]  (t via readlane from rres) ----
    float sc0, sc1;
    {
        v2f s0v = (v2f){0.f, 0.f}, s1v = s0v;
        const float* hl = &s_hid[l * 66];
        #pragma unroll
        for (int s = 0; s < 16; ++s) {
            const v2f hA = *(const v2f*)&hl[4 * s];
            const v2f hB = *(const v2f*)&hl[4 * s + 2];
            const v2f t0A = vmk(RL(rres.x, s),      RL(rres.y, s));
            const v2f t0B = vmk(RL(rres.z, s),      RL(rres.w, s));
            const v2f t1A = vmk(RL(rres.x, 32 + s), RL(rres.y, 32 + s));
            const v2f t1B = vmk(RL(rres.z, 32 + s), RL(rres.w, 32 + s));
            s0v = PKFMA(t0A, hA, PKFMA(t0B, hB, s0v));
            s1v = PKFMA(t1A, hA, PKFMA(t1B, hB, s1v));
        }
        sc0 = s0v.x + s0v.y;  sc1 = s1v.x + s1v.y;
    }

    // ---- phase 5: scores + packed softmax; q via readlane; attn -> aa[j][2] ----
    v2f aa2;
    {
        const float4 oj4 = *(const float4*)&s_obs[4 * l];
        const float4 oiA = *(const float4*)&s_obs[4 * (rg0 + 0)];
        const float4 oiB = *(const float4*)&s_obs[4 * (rg0 + 1)];
        const float rx0 = oj4.x - oiA.x, ry0 = oj4.y - oiA.y;
        const float dx0 = (oj4.z - oiA.z) * 4.f, dy0 = (oj4.w - oiA.w) * 4.f;
        const float rx1 = oj4.x - oiB.x, ry1 = oj4.y - oiB.y;
        const float dx1 = (oj4.z - oiB.z) * 4.f, dy1 = (oj4.w - oiB.w) * 4.f;
        v4f acc0 = {0,0,0,0}, acc1 = acc0;
        #pragma unroll
        for (int g = 0; g < 8; ++g) {
            const int s0 = 4 * g;
            const v4f w0p = *(const v4f*)&w_sp[s0];
            const v4f w1p = *(const v4f*)&w_sp[32 + s0];
            const v4f bsp = *(const v4f*)&b_sp[s0];
            const v4f u0p = *(const v4f*)&w_vel[s0];
            const v4f u1p = *(const v4f*)&w_vel[32 + s0];
            const v4f bvp = *(const v4f*)&b_vel[s0];
            const int lqs = 16 + g, lqd = 24 + g;
            const v4f q0s = {RL(rres.x, lqs), RL(rres.y, lqs), RL(rres.z, lqs), RL(rres.w, lqs)};
            const v4f q0d = {RL(rres.x, lqd), RL(rres.y, lqd), RL(rres.z, lqd), RL(rres.w, lqd)};
            const v4f q1s = {RL(rres.x, 32 + lqs), RL(rres.y, 32 + lqs),
                             RL(rres.z, 32 + lqs), RL(rres.w, 32 + lqs)};
            const v4f q1d = {RL(rres.x, 32 + lqd), RL(rres.y, 32 + lqd),
                             RL(rres.z, 32 + lqd), RL(rres.w, 32 + lqd)};
            const v4f esp0 = PKMAX(PKFMA(v4splat(rx0), w0p,
                                   PKFMA(v4splat(ry0), w1p, bsp)), v4splat(0.f));
            const v4f edv0 = PKMAX(PKFMA(v4splat(dx0), u0p,
                                   PKFMA(v4splat(dy0), u1p, bvp)), v4splat(0.f));
            acc0 = PKFMA(q0s, esp0, PKFMA(q0d, edv0, acc0));
            const v4f esp1 = PKMAX(PKFMA(v4splat(rx1), w0p,
                                   PKFMA(v4splat(ry1), w1p, bsp)), v4splat(0.f));
            const v4f edv1 = PKMAX(PKFMA(v4splat(dx1), u0p,
                                   PKFMA(v4splat(dy1), u1p, bvp)), v4splat(0.f));
            acc1 = PKFMA(q1s, esp1, PKFMA(q1d, edv1, acc1));
        }
        const float scale = 0.08838834764831845f;  // 1/sqrt(128)
        v2f p01 = vmk((sc0 + ((acc0.x + acc0.y) + (acc0.z + acc0.w))) * scale,
                      (sc1 + ((acc1.x + acc1.y) + (acc1.z + acc1.w))) * scale);
        v2f m01 = p01;
        #pragma unroll
        for (int off = 32; off > 0; off >>= 1)
            m01 = PKMAX(m01, shfl_xor_v2(m01, off));
        v2f e01 = vmk(__expf(p01.x - m01.x), __expf(p01.y - m01.y));
        v2f u01 = e01;
        #pragma unroll
        for (int off = 32; off > 0; off >>= 1)
            u01 = u01 + shfl_xor_v2(u01, off);
        aa2 = vmk(e01.x / u01.x, e01.y / u01.y);
        *(v2f*)&aa[2 * l] = aa2;      // consumed by 6a's j-split
    }

    // ---- phase 6a: pooled embeds -> pa[row][0:64] = [ssp 0..31 | sdv 32..63] ----
    // j-split (v7 form): lane (jh = l>>5, s = l&31) sums j in [32*jh, 32*jh+32) for BOTH rows.
    {
        const int jh = l >> 5, s = l & 31;
        const v2f wa = vmk(w_sp[s],      w_vel[s]);
        const v2f wb = vmk(w_sp[32 + s], w_vel[32 + s]);
        const v2f bb = vmk(b_sp[s],      b_vel[s]);
        const float4 oi0 = *(const float4*)&s_obs[4 * (rg0 + 0)];
        const float4 oi1 = *(const float4*)&s_obs[4 * (rg0 + 1)];
        v2f acc0 = (v2f){0.f, 0.f}, acc1 = acc0;
        const int j0 = 32 * jh;
        for (int j = j0; j < j0 + 32; ++j) {
            const v2f a2 = *(const v2f*)&aa[2 * j];
            const float4 o4 = *(const float4*)&s_obs[4 * j];
            {
                const v2f xx = vmk(o4.x - oi0.x, (o4.z - oi0.z) * 4.f);
                const v2f yy = vmk(o4.y - oi0.y, (o4.w - oi0.w) * 4.f);
                const v2f e2 = PKMAX(PKFMA(xx, wa, PKFMA(yy, wb, bb)), vsplat(0.f));
                acc0 = PKFMA(vsplat(a2.x), e2, acc0);
            }
            {
                const v2f xx = vmk(o4.x - oi1.x, (o4.z - oi1.z) * 4.f);
                const v2f yy = vmk(o4.y - oi1.y, (o4.w - oi1.w) * 4.f);
                const v2f e2 = PKMAX(PKFMA(xx, wa, PKFMA(yy, wb, bb)), vsplat(0.f));
                acc1 = PKFMA(vsplat(a2.y), e2, acc1);
            }
        }
        acc0 = red32_v2(acc0);
        acc1 = red32_v2(acc1);
        const v2f accw = jh ? acc1 : acc0;
        const int grow = (b * 64 + rg0 + jh) * 128;
        pa[grow + s]      = accw.x;   // ssp
        pa[grow + 32 + s] = accw.y;   // sdv
    }

    // ---- phase 6b: ah[r][l] = attn[r] @ hid -> pa[row][64+l]  (aa via readlane) ----
    {
        v2f ah = (v2f){0.f, 0.f};
        #pragma unroll 8
        for (int j = 0; j < 64; ++j) {
            const v2f a2 = vmk(RL(aa2.x, j), RL(aa2.y, j));   // {attn[0][j], attn[1][j]}
            ah = PKFMA(a2, vsplat(s_hid[j * 66 + l]), ah);
        }
        const int grow = (b * 64 + rg0) * 128;
        pa[grow + 64 + l]       = ah.x;
        pa[grow + 128 + 64 + l] = ah.y;
    }
}

// ---------------- out_gemm: out = poolah @ Fall + fb  (8192x128 @ 128x128) ----------------
// 256 blocks x 256 thr; block = 32 rows. Fall (64KB) + A rows (16KB) + fb staged in LDS.
// Thread: col pair c2 = 2*(tid&63), rows (tid>>6)*8 .. +7. A-row reads are wave-uniform
// (broadcast); Fall reads 512B/instr contiguous.
__global__ __launch_bounds__(256) void out_gemm(
    const float* __restrict__ ws, float* __restrict__ out)
{
    __shared__ __align__(16) float sF[16384 + 128 + 4096];
    float* const sFall = sF;
    float* const sfb   = sF + 16384;
    float* const sA    = sF + 16512;
    const int tid = threadIdx.x;
    const int r0 = blockIdx.x * 32;
    {
        const float4* src = (const float4*)(ws + WS_FALL);
        float4* dst = (float4*)sFall;
        #pragma unroll
        for (int k = tid; k < 4096; k += 256) dst[k] = src[k];
    }
    if (tid < 32) ((float4*)sfb)[tid] = ((const float4*)(ws + WS_FB))[tid];
    {
        const float4* src = (const float4*)(ws + WS_PA + r0 * 128);
        float4* dst = (float4*)sA;
        #pragma unroll
        for (int k = tid; k < 1024; k += 256) dst[k] = src[k];
    }
    __syncthreads();

    const int c2 = 2 * (tid & 63);
    const int rg = (tid >> 6) * 8;        // 8 rows per thread
    const v2f fb2 = *(const v2f*)&sfb[c2];
    v2f acc[8];
    #pragma unroll
    for (int r = 0; r < 8; ++r) acc[r] = fb2;
    for (int k = 0; k < 128; k += 4) {
        v4f a[8];
        #pragma unroll
        for (int r = 0; r < 8; ++r) a[r] = *(const v4f*)&sA[(rg + r) * 128 + k];
        #pragma unroll
        for (int kk = 0; kk < 4; ++kk) {
            const v2f f = *(const v2f*)&sFall[(k + kk) * 128 + c2];
            #pragma unroll
            for (int r = 0; r < 8; ++r)
                acc[r] = PKFMA(vsplat(a[r][kk]), f, acc[r]);
        }
    }
    const int gbase = (r0 + rg) * 128 + c2;
    #pragma unroll
    for (int r = 0; r < 8; ++r)
        *(v2f*)&out[gbase + r * 128] = acc[r];
}

extern "C" void kernel_launch(void* const* d_in, const int* in_sizes, int n_in,
                              void* d_out, int out_size, void* d_ws, size_t ws_size,
                              hipStream_t stream) {
    const float* hs        = (const float*)d_in[0];
    const float* obs1      = (const float*)d_in[1];
    const float* obs2      = (const float*)d_in[2];
    const float* w_sp      = (const float*)d_in[3];
    const float* b_sp      = (const float*)d_in[4];
    const float* w_vel     = (const float*)d_in[5];
    const float* b_vel     = (const float*)d_in[6];
    const float* w_hid     = (const float*)d_in[7];
    const float* b_hid     = (const float*)d_in[8];
    const float* wq        = (const float*)d_in[9];
    const float* wk        = (const float*)d_in[10];
    const float* wv        = (const float*)d_in[11];
    const float* in_proj_w = (const float*)d_in[12];
    const float* in_proj_b = (const float*)d_in[13];
    const float* mha_out_w = (const float*)d_in[14];
    const float* mha_out_b = (const float*)d_in[15];
    const float* out_w     = (const float*)d_in[16];
    const float* out_b     = (const float*)d_in[17];
    float* ws  = (float*)d_ws;
    float* out = (float*)d_out;

    const bool hidws = (ws_size >= WS_NEED_HID_BYTES);

    precompute1<<<hidws ? 512 : 256, 256, 0, stream>>>(
        wq, wk, wv, in_proj_w, mha_out_w, out_w, hs, w_hid, b_hid, ws);
    precompute2<<<194, 128, 0, stream>>>(
        b_sp, b_vel, in_proj_b, mha_out_b, out_w, out_b, ws);
    if (hidws) {
        attn_core<true><<<256, 1024, 0, stream>>>(hs, obs1, obs2, w_sp, b_sp, w_vel, b_vel,
                                                  w_hid, b_hid, ws, ws + WS_PA);
    } else {
        attn_core<false><<<256, 1024, 0, stream>>>(hs, obs1, obs2, w_sp, b_sp, w_vel, b_vel,
                                                   w_hid, b_hid, ws, ws + WS_PA);
    }
    out_gemm<<<256, 256, 0, stream>>>(ws, out);
}

// Round 7
// 125.664 us; speedup vs baseline: 1.0902x; 1.0902x over previous
//
#include <hip/hip_runtime.h>

typedef float v2f __attribute__((ext_vector_type(2)));
typedef float v4f __attribute__((ext_vector_type(4)));
#define PKFMA(a,b,c) __builtin_elementwise_fma((a),(b),(c))
#define PKMAX(a,b)   __builtin_elementwise_max((a),(b))
static __device__ __forceinline__ v2f vsplat(float s) { return (v2f){s, s}; }
static __device__ __forceinline__ v4f v4splat(float s) { return (v4f){s, s, s, s}; }
static __device__ __forceinline__ v2f vmk(float a, float b) { return (v2f){a, b}; }
static __device__ __forceinline__ v2f shfl_xor_v2(v2f x, int m) {
    double d = __builtin_bit_cast(double, x);
    d = __shfl_xor(d, m, 64);
    return __builtin_bit_cast(v2f, d);
}
// sum across the lane^32 split (both halves end with the full sum)
static __device__ __forceinline__ v2f red32_v2(v2f x) { return x + shfl_xor_v2(x, 32); }
static __device__ __forceinline__ v4f red32_v4(v4f x) {
    v2f lo = vmk(x.x, x.y), hi = vmk(x.z, x.w);
    lo = red32_v2(lo);  hi = red32_v2(hi);
    return (v4f){lo.x, lo.y, hi.x, hi.y};
}

// ---------------- workspace float offsets ----------------
#define WS_WQC   0        // wq@w_iq          128x128 row-major
#define WS_WKC   16384    // wk@w_ik          128x128 row-major
#define WS_WVC   32768    // wv@w_iv          128x128 row-major
#define WS_MOW   49152    // mha_out_w@out_w  128x128 row-major
#define WS_GQ    65536    // [64][128]: cols 0..63 G, 64..95 Gs, 96..127 Gd
#define WS_G0Q   73728    // [128] biases in same col order
#define WS_FALL  73856    // [128][128]: rows 0..31 Fsp, 32..63 Fdv, 64..127 Fhid
#define WS_FB    90240    // [128]
#define WS_HID   90368    // [128 batches][64][64] relu(hs@w_hid+b_hid)
#define WS_NEED_HID_BYTES ((size_t)(90368 + 128*64*64) * 4)

// P1: weight products (+ per-batch hid into ws when workspace allows)
__global__ __launch_bounds__(256) void precompute1(
    const float* __restrict__ wq, const float* __restrict__ wk,
    const float* __restrict__ wv, const float* __restrict__ in_proj_w,
    const float* __restrict__ mha_out_w, const float* __restrict__ out_w,
    const float* __restrict__ hs, const float* __restrict__ w_hid,
    const float* __restrict__ b_hid, float* __restrict__ ws)
{
    __shared__ __align__(16) float sbuf[4224];
    const int tid = threadIdx.x;

    if (blockIdx.x < 256) {
        const int mat  = blockIdx.x >> 6;
        const int rp   = blockIdx.x & 63;
        const int rsel = tid >> 7;
        const int col  = tid & 127;
        const int r    = 2 * rp + rsel;
        const float* A; const float* Bm; int ldb; float* C;
        if (mat == 0)      { A = wq;        Bm = in_proj_w;       ldb = 384; C = ws + WS_WQC; }
        else if (mat == 1) { A = wk;        Bm = in_proj_w + 128; ldb = 384; C = ws + WS_WKC; }
        else if (mat == 2) { A = wv;        Bm = in_proj_w + 256; ldb = 384; C = ws + WS_WVC; }
        else               { A = mha_out_w; Bm = out_w;           ldb = 128; C = ws + WS_MOW; }
        sbuf[tid] = A[r * 128 + col];
        __syncthreads();
        float acc = 0.f;
        #pragma unroll 8
        for (int d = 0; d < 128; ++d) acc = fmaf(sbuf[rsel * 128 + d], Bm[d * ldb + col], acc);
        C[r * 128 + col] = acc;
    } else {
        const int b2 = blockIdx.x - 256;
        const int b = b2 >> 1, half = b2 & 1;
        const float4* src = (const float4*)(hs + b * 8192 + half * 4096);
        for (int k = tid; k < 1024; k += 256) {
            const int row = k >> 5, c = k & 31;
            *(float4*)&sbuf[row * 132 + 4 * c] = src[k];
        }
        __syncthreads();
        const int ty = tid >> 4, tx = tid & 15;
        float a0c[4] = {0,0,0,0}, a1c[4] = {0,0,0,0};
        for (int d0 = 0; d0 < 128; d0 += 4) {
            const float4 a0 = *(const float4*)&sbuf[(2*ty+0)*132 + d0];
            const float4 a1 = *(const float4*)&sbuf[(2*ty+1)*132 + d0];
            const float* a0p = (const float*)&a0;
            const float* a1p = (const float*)&a1;
            #pragma unroll
            for (int dd = 0; dd < 4; ++dd) {
                const float4 w4 = *(const float4*)&w_hid[(d0+dd)*64 + 4*tx];
                a0c[0] = fmaf(a0p[dd], w4.x, a0c[0]); a0c[1] = fmaf(a0p[dd], w4.y, a0c[1]);
                a0c[2] = fmaf(a0p[dd], w4.z, a0c[2]); a0c[3] = fmaf(a0p[dd], w4.w, a0c[3]);
                a1c[0] = fmaf(a1p[dd], w4.x, a1c[0]); a1c[1] = fmaf(a1p[dd], w4.y, a1c[1]);
                a1c[2] = fmaf(a1p[dd], w4.z, a1c[2]); a1c[3] = fmaf(a1p[dd], w4.w, a1c[3]);
            }
        }
        const float4 bh = *(const float4*)&b_hid[4*tx];
        float* dst = ws + WS_HID + b * 4096 + (32*half + 2*ty) * 64 + 4*tx;
        *(float4*)dst        = make_float4(fmaxf(a0c[0]+bh.x,0.f), fmaxf(a0c[1]+bh.y,0.f),
                                           fmaxf(a0c[2]+bh.z,0.f), fmaxf(a0c[3]+bh.w,0.f));
        *(float4*)(dst + 64) = make_float4(fmaxf(a1c[0]+bh.x,0.f), fmaxf(a1c[1]+bh.y,0.f),
                                           fmaxf(a1c[2]+bh.z,0.f), fmaxf(a1c[3]+bh.w,0.f));
    }
}

// P2: derived fused tensors GQ / g0q / F_all / fb (float4 row reads)
__global__ __launch_bounds__(128) void precompute2(
    const float* __restrict__ b_sp, const float* __restrict__ b_vel,
    const float* __restrict__ in_proj_b, const float* __restrict__ mha_out_b,
    const float* __restrict__ out_w, const float* __restrict__ out_b,
    float* __restrict__ ws)
{
    const float* Wqc = ws + WS_WQC;
    const float* Wkc = ws + WS_WKC;
    const float* Wvc = ws + WS_WVC;
    const float* Mow = ws + WS_MOW;
    const int bid = blockIdx.x, tid = threadIdx.x;
    __shared__ __align__(16) float sa[128];

    if (bid < 64) {
        const int k = bid;
        sa[tid] = Wqc[(32 + k) * 128 + tid];
        __syncthreads();
        const int j = tid;
        const int pj = (j < 64) ? 32 + j : ((j < 96) ? j - 64 : j);
        const float* brow = Wkc + pj * 128;
        float acc = 0.f;
        #pragma unroll 8
        for (int d = 0; d < 128; d += 4) {
            const float4 a4 = *(const float4*)&sa[d];
            const float4 b4 = *(const float4*)&brow[d];
            acc = fmaf(a4.x, b4.x, fmaf(a4.y, b4.y, fmaf(a4.z, b4.z, fmaf(a4.w, b4.w, acc))));
        }
        ws[WS_GQ + k * 128 + j] = acc;
    } else if (bid < 192) {
        const int k2 = bid - 64;
        const int srcRow = (k2 < 32) ? k2 : ((k2 < 64) ? 96 + (k2 - 32) : 32 + (k2 - 64));
        sa[tid] = Wvc[srcRow * 128 + tid];
        __syncthreads();
        float acc = 0.f;
        #pragma unroll 8
        for (int m = 0; m < 128; ++m) acc = fmaf(sa[m], Mow[m * 128 + tid], acc);
        ws[WS_FALL + k2 * 128 + tid] = acc;
    } else if (bid == 192) {
        float acc = out_b[tid];
        #pragma unroll 8
        for (int m = 0; m < 128; ++m) {
            acc = fmaf(in_proj_b[256 + m], Mow[m * 128 + tid], acc);
            acc = fmaf(mha_out_b[m], out_w[m * 128 + tid], acc);
        }
        ws[WS_FB + tid] = acc;
    } else {
        float qc = in_proj_b[tid];  // b_iq
        #pragma unroll 4
        for (int s = 0; s < 32; ++s) {
            qc = fmaf(fmaxf(b_sp[s], 0.f),  Wqc[s * 128 + tid], qc);
            qc = fmaf(fmaxf(b_vel[s], 0.f), Wqc[(96 + s) * 128 + tid], qc);
        }
        sa[tid] = qc;
        __syncthreads();
        const int j = tid;
        const int pj = (j < 64) ? 32 + j : ((j < 96) ? j - 64 : j);
        const float* brow = Wkc + pj * 128;
        float acc = 0.f;
        #pragma unroll 8
        for (int d = 0; d < 128; d += 4) {
            const float4 a4 = *(const float4*)&sa[d];
            const float4 b4 = *(const float4*)&brow[d];
            acc = fmaf(a4.x, b4.x, fmaf(a4.y, b4.y, fmaf(a4.z, b4.z, fmaf(a4.w, b4.w, acc))));
        }
        ws[WS_G0Q + j] = acc;
    }
}

// ---------------- attn_main v7 (measured best, 123.8 us total): k-split + b128 ----------------
// Across v5-v10: occupancy doubling (v6), LDS-instr -30% (v7), LDS->VALU readlane
// (v8/v9), kernel fission (v10) -> only v7 improved. This is the empirical optimum;
// restored verbatim.
#define L_GQ   0        // [64][128]
#define L_G0Q  8192     // [128]
#define L_FALL 8320     // [128][128]
#define L_FB   24704    // [128]
#define L_HID  24832    // [64][66] (stride-66 padded)
#define L_OBS  29056    // [64][4] = {o2x,o2y,vx,vy}
#define L_WV   29312    // + w*384 : tt[2][64] | qq[2][64] | aa[64][2]
#define L_TOT  35456    // floats = 141,824 B  (<= 160 KB gfx950 workgroup LDS)

template <bool HIDWS>
__global__ __launch_bounds__(1024) void attn_main(
    const float* __restrict__ hs, const float* __restrict__ obs1,
    const float* __restrict__ obs2,
    const float* __restrict__ w_sp, const float* __restrict__ b_sp,
    const float* __restrict__ w_vel, const float* __restrict__ b_vel,
    const float* __restrict__ w_hid, const float* __restrict__ b_hid,
    const float* __restrict__ ws, float* __restrict__ out)
{
    const int tid = threadIdx.x;
    const int l   = tid & 63;
    const int w   = tid >> 6;                 // 0..15
    const int b   = blockIdx.x >> 1;
    const int rg0 = (blockIdx.x & 1) * 32 + 2 * w;   // 2 rows: rg0, rg0+1 (rg0 even)

    __shared__ __align__(16) float smem[L_TOT];
    float* const s_gq  = smem + L_GQ;
    float* const s_g0q = smem + L_G0Q;
    float* const s_fall= smem + L_FALL;
    float* const s_fb  = smem + L_FB;
    float* const s_hid = smem + L_HID;            // stride 66
    float* const s_obs = smem + L_OBS;
    float* const tt = smem + L_WV + w * 384;      // [2][64]  (t, later pooled embeds)
    float* const qq = smem + L_WV + w * 384 + 128;// [2][qs32|qd32] (later ah)
    float* const aa = smem + L_WV + w * 384 + 256;// [j][2]

    // ---- staging: ws[WS_GQ .. WS_GQ+24832) is contiguous = GQ|g0q|Fall|fb ----
    {
        const float4* src = (const float4*)(ws + WS_GQ);
        float4* dst = (float4*)smem;
        #pragma unroll
        for (int k = tid; k < 6208; k += 1024) dst[k] = src[k];
    }
    if (tid < 64) {
        const int g = b * 64 + tid;
        const float2 o2 = ((const float2*)obs2)[g];
        const float2 o1 = ((const float2*)obs1)[g];
        *(float4*)&s_obs[tid * 4] = make_float4(o2.x, o2.y, o2.x - o1.x, o2.y - o1.y);
    }
    if (HIDWS) {
        const float4* src = (const float4*)(ws + WS_HID + b * 4096);
        {
            const int k = tid;   // exactly 1024 float4s
            const int row = k >> 4, c4 = (k & 15) * 4;
            const float4 v = src[k];
            *(v2f*)&s_hid[row * 66 + c4]     = vmk(v.x, v.y);
            *(v2f*)&s_hid[row * 66 + c4 + 2] = vmk(v.z, v.w);
        }
    } else {
        const int r = tid >> 4, c0 = (tid & 15) * 4;
        float acc[4];
        #pragma unroll
        for (int c = 0; c < 4; ++c) acc[c] = b_hid[c0 + c];
        for (int k = 0; k < 128; ++k) {
            const float a = hs[b * 8192 + r * 128 + k];
            const float4 w4 = *(const float4*)&w_hid[k * 64 + c0];
            acc[0] = fmaf(a, w4.x, acc[0]);
            acc[1] = fmaf(a, w4.y, acc[1]);
            acc[2] = fmaf(a, w4.z, acc[2]);
            acc[3] = fmaf(a, w4.w, acc[3]);
        }
        *(v2f*)&s_hid[r * 66 + c0]     = vmk(fmaxf(acc[0], 0.f), fmaxf(acc[1], 0.f));
        *(v2f*)&s_hid[r * 66 + c0 + 2] = vmk(fmaxf(acc[2], 0.f), fmaxf(acc[3], 0.f));
    }
    __syncthreads();
    // ---- no more block barriers: wave-private phases below ----

    const int kh = l >> 5;            // k-half selector (reused per phase)
    const int cg = (l & 31) * 4;      // 4-col group
    const int hsel = l >> 5;          // row selector for writes after reduction

    // ---- phase 3: [t | qs | qd](2x128) = hid[rg0..rg0+1] @ GQ + g0q ----
    // k-split: lane sums k in [32*kh, 32*kh+32) for cols cg..cg+3, both rows.
    {
        v4f acc0 = {0,0,0,0}, acc1 = acc0;
        const int kb = 32 * kh;
        #pragma unroll
        for (int c8 = 0; c8 < 32; c8 += 8) {
            v2f h0[4], h1[4];
            #pragma unroll
            for (int j = 0; j < 4; ++j) {
                h0[j] = *(const v2f*)&s_hid[(rg0 + 0) * 66 + kb + c8 + 2 * j];
                h1[j] = *(const v2f*)&s_hid[(rg0 + 1) * 66 + kb + c8 + 2 * j];
            }
            #pragma unroll
            for (int j = 0; j < 4; ++j) {
                const int kk = kb + c8 + 2 * j;
                const v4f ga = *(const v4f*)&s_gq[kk * 128 + cg];
                const v4f gb = *(const v4f*)&s_gq[(kk + 1) * 128 + cg];
                acc0 = PKFMA(v4splat(h0[j].x), ga, PKFMA(v4splat(h0[j].y), gb, acc0));
                acc1 = PKFMA(v4splat(h1[j].x), ga, PKFMA(v4splat(h1[j].y), gb, acc1));
            }
        }
        acc0 = red32_v4(acc0);
        acc1 = red32_v4(acc1);
        const v4f bias = *(const v4f*)&s_g0q[cg];
        const v4f r = (hsel ? acc1 : acc0) + bias;
        if (cg < 64) *(v4f*)&tt[hsel * 64 + cg]        = r;
        else         *(v4f*)&qq[hsel * 64 + (cg - 64)] = r;
    }

    // ---- phase 4: sc[r] = t[r] . hid[l] ----
    float sc0, sc1;
    {
        v2f s0 = (v2f){0.f, 0.f}, s1 = s0;
        const float* hl = &s_hid[l * 66];
        for (int c0 = 0; c0 < 64; c0 += 2) {
            const v2f h2 = *(const v2f*)&hl[c0];
            s0 = PKFMA(*(const v2f*)&tt[c0], h2, s0);
            s1 = PKFMA(*(const v2f*)&tt[64 + c0], h2, s1);
        }
        sc0 = s0.x + s0.y;  sc1 = s1.x + s1.y;
    }

    // ---- phase 5: scores + packed softmax (rows 0,1 in one v2f); attn -> aa[j][2] ----
    {
        const float4 oj = *(const float4*)&s_obs[4 * l];
        float rx[2], ry[2], dx[2], dy[2];
        #pragma unroll
        for (int r = 0; r < 2; ++r) {
            const float4 oi = *(const float4*)&s_obs[4 * (rg0 + r)];
            rx[r] = oj.x - oi.x;  ry[r] = oj.y - oi.y;
            dx[r] = (oj.z - oi.z) * 4.f;  dy[r] = (oj.w - oi.w) * 4.f;
        }
        v2f acc[2] = {{0,0},{0,0}};
        for (int s0 = 0; s0 < 32; s0 += 2) {
            const v2f w0p = *(const v2f*)&w_sp[s0];
            const v2f w1p = *(const v2f*)&w_sp[32 + s0];
            const v2f bsp = *(const v2f*)&b_sp[s0];
            const v2f u0p = *(const v2f*)&w_vel[s0];
            const v2f u1p = *(const v2f*)&w_vel[32 + s0];
            const v2f bvp = *(const v2f*)&b_vel[s0];
            #pragma unroll
            for (int r = 0; r < 2; ++r) {
                const v2f qs2 = *(const v2f*)&qq[r * 64 + s0];
                const v2f qd2 = *(const v2f*)&qq[r * 64 + 32 + s0];
                const v2f esp = PKMAX(PKFMA(vsplat(rx[r]), w0p,
                                     PKFMA(vsplat(ry[r]), w1p, bsp)), vsplat(0.f));
                acc[r] = PKFMA(qs2, esp, acc[r]);
                const v2f edv = PKMAX(PKFMA(vsplat(dx[r]), u0p,
                                     PKFMA(vsplat(dy[r]), u1p, bvp)), vsplat(0.f));
                acc[r] = PKFMA(qd2, edv, acc[r]);
            }
        }
        const float scale = 0.08838834764831845f;  // 1/sqrt(128)
        v2f p01 = vmk((sc0 + acc[0].x + acc[0].y) * scale,
                      (sc1 + acc[1].x + acc[1].y) * scale);
        v2f m01 = p01;
        #pragma unroll
        for (int off = 32; off > 0; off >>= 1)
            m01 = PKMAX(m01, shfl_xor_v2(m01, off));
        v2f e01 = vmk(__expf(p01.x - m01.x), __expf(p01.y - m01.y));
        v2f u01 = e01;
        #pragma unroll
        for (int off = 32; off > 0; off >>= 1)
            u01 = u01 + shfl_xor_v2(u01, off);
        *(v2f*)&aa[2 * l] = vmk(e01.x / u01.x, e01.y / u01.y);
    }

    // ---- phase 6a: pooled embeds -> tt[r] = [ssp 0..31 | sdv 32..63] ----
    // j-split: lane (jh = l>>5, s = l&31) sums j in [32*jh, 32*jh+32) for BOTH rows.
    {
        const int jh = l >> 5, s = l & 31;
        const v2f wa = vmk(w_sp[s],      w_vel[s]);
        const v2f wb = vmk(w_sp[32 + s], w_vel[32 + s]);
        const v2f bb = vmk(b_sp[s],      b_vel[s]);
        const float4 oi0 = *(const float4*)&s_obs[4 * (rg0 + 0)];
        const float4 oi1 = *(const float4*)&s_obs[4 * (rg0 + 1)];
        v2f acc0 = (v2f){0.f, 0.f}, acc1 = acc0;
        const int j0 = 32 * jh;
        for (int j = j0; j < j0 + 32; ++j) {
            const v2f a2 = *(const v2f*)&aa[2 * j];
            const float4 o4 = *(const float4*)&s_obs[4 * j];
            {
                const v2f xx = vmk(o4.x - oi0.x, (o4.z - oi0.z) * 4.f);
                const v2f yy = vmk(o4.y - oi0.y, (o4.w - oi0.w) * 4.f);
                const v2f e2 = PKMAX(PKFMA(xx, wa, PKFMA(yy, wb, bb)), vsplat(0.f));
                acc0 = PKFMA(vsplat(a2.x), e2, acc0);
            }
            {
                const v2f xx = vmk(o4.x - oi1.x, (o4.z - oi1.z) * 4.f);
                const v2f yy = vmk(o4.y - oi1.y, (o4.w - oi1.w) * 4.f);
                const v2f e2 = PKMAX(PKFMA(xx, wa, PKFMA(yy, wb, bb)), vsplat(0.f));
                acc1 = PKFMA(vsplat(a2.y), e2, acc1);
            }
        }
        acc0 = red32_v2(acc0);
        acc1 = red32_v2(acc1);
        const v2f accw = jh ? acc1 : acc0;
        tt[jh * 64 + s]      = accw.x;   // ssp
        tt[jh * 64 + 32 + s] = accw.y;   // sdv
    }

    // ---- phase 6b: ah[r][l] = attn[r] @ hid -> qq[r][l] (packed over r) ----
    {
        v2f ah = (v2f){0.f, 0.f};
        for (int j = 0; j < 64; j += 2) {
            const v2f a0 = *(const v2f*)&aa[2 * j];       // {a[j][0], a[j][1]}
            const v2f a1 = *(const v2f*)&aa[2 * j + 2];
            const float h0 = s_hid[j * 66 + l];
            const float h1 = s_hid[(j + 1) * 66 + l];
            ah = PKFMA(a0, vsplat(h0), PKFMA(a1, vsplat(h1), ah));
        }
        qq[l] = ah.x;  qq[64 + l] = ah.y;
    }

    // ---- phase 7: out = [ssp|sdv] @ Fall[0:64] + ah @ Fall[64:128] + fb ----
    // k-split: kh=0 -> A rows from tt (k 0..63), kh=1 -> from qq (k 64..127).
    {
        const float* Asrc = kh ? qq : tt;
        v4f acc0 = {0,0,0,0}, acc1 = acc0;
        #pragma unroll
        for (int c8 = 0; c8 < 64; c8 += 8) {
            v2f a0[4], a1[4];
            #pragma unroll
            for (int j = 0; j < 4; ++j) {
                a0[j] = *(const v2f*)&Asrc[c8 + 2 * j];
                a1[j] = *(const v2f*)&Asrc[64 + c8 + 2 * j];
            }
            #pragma unroll
            for (int j = 0; j < 4; ++j) {
                const int kk = 64 * kh + c8 + 2 * j;
                const v4f fa = *(const v4f*)&s_fall[kk * 128 + cg];
                const v4f fc = *(const v4f*)&s_fall[(kk + 1) * 128 + cg];
                acc0 = PKFMA(v4splat(a0[j].x), fa, PKFMA(v4splat(a0[j].y), fc, acc0));
                acc1 = PKFMA(v4splat(a1[j].x), fa, PKFMA(v4splat(a1[j].y), fc, acc1));
            }
        }
        acc0 = red32_v4(acc0);
        acc1 = red32_v4(acc1);
        const v4f fb4 = *(const v4f*)&s_fb[cg];
        const v4f o = (hsel ? acc1 : acc0) + fb4;
        const int gr = (b * 64 + rg0 + hsel) * 128 + cg;
        *(v4f*)&out[gr] = o;
    }
}

extern "C" void kernel_launch(void* const* d_in, const int* in_sizes, int n_in,
                              void* d_out, int out_size, void* d_ws, size_t ws_size,
                              hipStream_t stream) {
    const float* hs        = (const float*)d_in[0];
    const float* obs1      = (const float*)d_in[1];
    const float* obs2      = (const float*)d_in[2];
    const float* w_sp      = (const float*)d_in[3];
    const float* b_sp      = (const float*)d_in[4];
    const float* w_vel     = (const float*)d_in[5];
    const float* b_vel     = (const float*)d_in[6];
    const float* w_hid     = (const float*)d_in[7];
    const float* b_hid     = (const float*)d_in[8];
    const float* wq        = (const float*)d_in[9];
    const float* wk        = (const float*)d_in[10];
    const float* wv        = (const float*)d_in[11];
    const float* in_proj_w = (const float*)d_in[12];
    const float* in_proj_b = (const float*)d_in[13];
    const float* mha_out_w = (const float*)d_in[14];
    const float* mha_out_b = (const float*)d_in[15];
    const float* out_w     = (const float*)d_in[16];
    const float* out_b     = (const float*)d_in[17];
    float* ws  = (float*)d_ws;
    float* out = (float*)d_out;

    const bool hidws = (ws_size >= WS_NEED_HID_BYTES);

    precompute1<<<hidws ? 512 : 256, 256, 0, stream>>>(
        wq, wk, wv, in_proj_w, mha_out_w, out_w, hs, w_hid, b_hid, ws);
    precompute2<<<194, 128, 0, stream>>>(
        b_sp, b_vel, in_proj_b, mha_out_b, out_w, out_b, ws);
    if (hidws) {
        attn_main<true><<<256, 1024, 0, stream>>>(hs, obs1, obs2, w_sp, b_sp, w_vel, b_vel,
                                                  w_hid, b_hid, ws, out);
    } else {
        attn_main<false><<<256, 1024, 0, stream>>>(hs, obs1, obs2, w_sp, b_sp, w_vel, b_vel,
                                                   w_hid, b_hid, ws, out);
    }
}